// Round 7
// baseline (107.645 us; speedup 1.0000x reference)
//
#include <hip/hip_runtime.h>
#include <stdint.h>

typedef _Float16 h2 __attribute__((ext_vector_type(2)));
typedef _Float16 h8 __attribute__((ext_vector_type(8)));
typedef float f32x4 __attribute__((ext_vector_type(4)));
typedef unsigned int u32;
typedef unsigned short u16;

// LDS strides (in elements of the buffer's type)
#define WT_STR 68    // WaT  [c'=256][h]   u16 ; 136B rows
#define PJ_STR 68    // pjT  [n*64+j][h]   u16 ; 136B rows
#define WP_STR 268   // WpT  [o=64][c2]    u16 ; 536B rows
#define PI_STR 36    // sPi  [n][i<16][h2] u32 ; 144B rows
#define CB_STR 72    // cb   [j=64][h]     u16 ; 144B rows
#define CT_STR 68    // ct   [h=64][j]     u16 ; 136B rows
#define AB_STR 72    // ab   [m=64][j]     u16 ; 144B rows
#define CS_STR 264   // cs   [i=16][c2]    u16 ; 528B rows
#define WS_STR 36    // ws   [n=4][h2]     u32 ; 144B rows

#define POISON_INT ((int)0xAAAAAAAA)   // harness poisons d_ws bytes with 0xAA

__device__ __forceinline__ u32 pk2(float a, float b) {
    return __builtin_bit_cast(u32, __builtin_amdgcn_cvt_pkrtz(a, b));
}
__device__ __forceinline__ h8 frag4(u32 a, u32 b, u32 c, u32 d) {
    return __builtin_bit_cast(h8, make_uint4(a, b, c, d));
}

__global__ __launch_bounds__(512, 1) void atom_attn(
    const float* __restrict__ inputs,
    const int*   __restrict__ scope,
    const float* __restrict__ Wa_pair,
    const float* __restrict__ Wa_score,
    const float* __restrict__ W_proj,
    float* __restrict__ out_mol,    // [64][64]
    float* __restrict__ out_flat,   // [N+1][64]
    float* __restrict__ ws_part,    // [64 mol][4 bx][64 o] partials (d_ws)
    int*   __restrict__ ws_cnt)     // [64 mol] arrival counters (d_ws, poison-init)
{
    // Separate buffers — no aliasing, no extra barriers. Total ~149 KB -> 1 block/CU.
    __shared__ __align__(16) u16 s_wa[256 * WT_STR];         // 34,816 B
    __shared__ __align__(16) u16 s_pj[256 * PJ_STR];         // 34,816 B
    __shared__ __align__(16) u16 s_wp[64 * WP_STR];          // 34,304 B
    __shared__ __align__(16) u32 s_pi[4 * 16 * PI_STR];      //  9,216 B
    __shared__ __align__(16) u16 s_cb[64 * CB_STR];          //  9,216 B
    __shared__ __align__(16) u16 s_ct[64 * CT_STR];          //  8,704 B
    __shared__ __align__(16) u16 s_ab[64 * AB_STR];          //  9,216 B
    __shared__ __align__(16) u16 s_cs[16 * CS_STR];          //  8,448 B
    __shared__ __align__(16) u32 s_ws[4 * WS_STR];           //    576 B
    __shared__ int s_last;

    const int t = threadIdx.x;
    const int w = t >> 6, l = t & 63;
    const int ml = l & 15, q = l >> 4;
    const int b = blockIdx.y, bx = blockIdx.x;
    const int i_base = bx * 16;

    // ================= Phase 0: stage everything (ws, c, WaT, WpT) =================
    if (t < 256) {
        if (t < 128) {  // ws transposed+packed: s_ws[n][h2] = (ws[2h2,n], ws[2h2+1,n])
            const int n = t & 3, hh = t >> 2;
            const float g0 = Wa_score[(2 * hh) * 4 + n];
            const float g1 = Wa_score[(2 * hh + 1) * 4 + n];
            s_ws[n * WS_STR + hh] = pk2(g0, g1);
        }
        {   // c rows -> cb [j][h] (h-packed) and ct [h][j] (j-pair packed)
            const int jp = (t & 31) * 2;
            const int pp = t >> 5;           // h-octant 0..7
            const int r0 = scope[b * 64 + jp];
            const int r1 = scope[b * 64 + jp + 1];
            const f32x4 a0 = *(const f32x4*)(inputs + (size_t)r0 * 64 + pp * 8);
            const f32x4 a1 = *(const f32x4*)(inputs + (size_t)r0 * 64 + pp * 8 + 4);
            const f32x4 b0 = *(const f32x4*)(inputs + (size_t)r1 * 64 + pp * 8);
            const f32x4 b1 = *(const f32x4*)(inputs + (size_t)r1 * 64 + pp * 8 + 4);
            float A[8] = {a0[0], a0[1], a0[2], a0[3], a1[0], a1[1], a1[2], a1[3]};
            float B[8] = {b0[0], b0[1], b0[2], b0[3], b1[0], b1[1], b1[2], b1[3]};
            *(uint4*)&s_cb[jp * CB_STR + pp * 8] =
                make_uint4(pk2(A[0], A[1]), pk2(A[2], A[3]), pk2(A[4], A[5]), pk2(A[6], A[7]));
            *(uint4*)&s_cb[(jp + 1) * CB_STR + pp * 8] =
                make_uint4(pk2(B[0], B[1]), pk2(B[2], B[3]), pk2(B[4], B[5]), pk2(B[6], B[7]));
            #pragma unroll
            for (int e = 0; e < 8; ++e)
                *(u32*)&s_ct[(pp * 8 + e) * CT_STR + jp] = pk2(A[e], B[e]);
        }
        {   // WpT[o][c2] f16
            const int o0 = (t & 31) * 2, seg = t >> 5;
            #pragma unroll
            for (int k2 = 0; k2 < 16; ++k2) {
                const int c0 = seg * 32 + k2 * 2;
                const float2 r0 = *(const float2*)(W_proj + c0 * 64 + o0);
                const float2 r1 = *(const float2*)(W_proj + (c0 + 1) * 64 + o0);
                *(u32*)&s_wp[o0 * WP_STR + c0]       = pk2(r0.x, r1.x);
                *(u32*)&s_wp[(o0 + 1) * WP_STR + c0] = pk2(r0.y, r1.y);
            }
        }
    } else {
        // WaT[c'][h] f16, c' = (c&3)*64 + (c>>2)  (n-major column permutation)
        const int t2 = t & 255;
        const int cg = (t2 & 127) * 2;       // even global column
        const int hh2 = t2 >> 7;             // h half
        const int cp0 = (cg & 3) * 64 + (cg >> 2);   // dest row for cg; cg+1 -> +64
        #pragma unroll
        for (int k2 = 0; k2 < 16; ++k2) {
            const int h0 = hh2 * 32 + k2 * 2;
            const float2 r0 = *(const float2*)(Wa_pair + h0 * 256 + cg);
            const float2 r1 = *(const float2*)(Wa_pair + (h0 + 1) * 256 + cg);
            *(u32*)&s_wa[cp0 * WT_STR + h0]        = pk2(r0.x, r1.x);
            *(u32*)&s_wa[(cp0 + 64) * WT_STR + h0] = pk2(r0.y, r1.y);
        }
    }
    __syncthreads();

    // ================= Phase 1: D = P^T (M=c'=256, N=j=64, K=h=64), 8 waves =================
    // wave: mq = w&3 -> mt in [mq*4, mq*4+4); jh = w>>2 -> j-tiles {2jh, 2jh+1}
    {
        const int mq = w & 3, jh = w >> 2;
        f32x4 D[4][2];
        #pragma unroll
        for (int k = 0; k < 4; ++k) { D[k][0] = (f32x4)0.f; D[k][1] = (f32x4)0.f; }
        h8 bf[2][2];
        #pragma unroll
        for (int jt = 0; jt < 2; ++jt)
            #pragma unroll
            for (int ks = 0; ks < 2; ++ks)
                bf[jt][ks] = __builtin_bit_cast(h8,
                    *(const uint4*)&s_cb[((jh * 2 + jt) * 16 + ml) * CB_STR + ks * 32 + q * 8]);
        #pragma unroll
        for (int k = 0; k < 4; ++k) {
            const int mt = mq * 4 + k;
            #pragma unroll
            for (int ks = 0; ks < 2; ++ks) {
                const uint2 x0 = *(const uint2*)&s_wa[(mt * 16 + ml) * WT_STR + ks * 32 + q * 8];
                const uint2 x1 = *(const uint2*)&s_wa[(mt * 16 + ml) * WT_STR + ks * 32 + q * 8 + 4];
                const h8 af = frag4(x0.x, x0.y, x1.x, x1.y);
                D[k][0] = __builtin_amdgcn_mfma_f32_16x16x32_f16(af, bf[0][ks], D[k][0], 0, 0, 0);
                D[k][1] = __builtin_amdgcn_mfma_f32_16x16x32_f16(af, bf[1][ks], D[k][1], 0, 0, 0);
            }
        }
        // store P^T (separate buffers -> no barrier needed before stores)
        #pragma unroll
        for (int k = 0; k < 4; ++k) {
            const int mt = mq * 4 + k;
            const int nb = mt >> 2, h0 = (mt & 3) * 16 + q * 4;
            #pragma unroll
            for (int jt = 0; jt < 2; ++jt) {
                const int jtile = jh * 2 + jt;
                const int j = jtile * 16 + ml;
                const u32 p0 = pk2(D[k][jt][0], D[k][jt][1]);
                const u32 p1 = pk2(D[k][jt][2], D[k][jt][3]);
                *(uint2*)&s_pj[(nb * 64 + j) * PJ_STR + h0] = make_uint2(p0, p1);
                if (jtile == bx)   // j == i_base + ml -> this block's P_i rows
                    *(uint2*)&s_pi[(nb * 16 + ml) * PI_STR + (h0 >> 1)] = make_uint2(p0, p1);
            }
        }
    }
    __syncthreads();

    // ================= Phase 2: scores (wave = (n, i-half), lane = j) =================
    {
        const int n = w & 3, ih = w >> 2;
        u32 pj_u[32];
        #pragma unroll
        for (int k = 0; k < 16; ++k) {
            const uint2 v = *(const uint2*)&s_pj[(n * 64 + l) * PJ_STR + k * 4];
            pj_u[2 * k] = v.x; pj_u[2 * k + 1] = v.y;
        }
        u32 ws_u[32];
        #pragma unroll
        for (int k = 0; k < 8; ++k) {
            const uint4 v = *(const uint4*)&s_ws[n * WS_STR + k * 4];
            ws_u[4 * k] = v.x; ws_u[4 * k + 1] = v.y; ws_u[4 * k + 2] = v.z; ws_u[4 * k + 3] = v.w;
        }
        const h2 zero2 = {(_Float16)0.f, (_Float16)0.f};
        #pragma unroll
        for (int ii = 0; ii < 8; ++ii) {
            const int iloc = ih * 8 + ii;
            const u32* pir = &s_pi[(n * 16 + iloc) * PI_STR];
            float s0 = 0.f, s1 = 0.f;
            #pragma unroll
            for (int c8 = 0; c8 < 8; ++c8) {
                const uint4 pv = *(const uint4*)&pir[c8 * 4];
                const u32 pe[4] = {pv.x, pv.y, pv.z, pv.w};
                #pragma unroll
                for (int e = 0; e < 4; ++e) {
                    const h2 pi2 = __builtin_bit_cast(h2, pe[e]);
                    const h2 pj2 = __builtin_bit_cast(h2, pj_u[c8 * 4 + e]);
                    h2 tv = pi2 + pj2;                         // v_pk_add_f16
                    tv = __builtin_elementwise_max(tv, zero2); // v_pk_max_f16
                    if (e & 1)
                        s1 = __builtin_amdgcn_fdot2(tv,
                                __builtin_bit_cast(h2, ws_u[c8 * 4 + e]), s1, false);
                    else
                        s0 = __builtin_amdgcn_fdot2(tv,
                                __builtin_bit_cast(h2, ws_u[c8 * 4 + e]), s0, false);
                }
            }
            const float s = s0 + s1;
            const float a = 1.f / (1.f + __expf(-s));
            const _Float16 ah = (_Float16)a;
            s_ab[(iloc * 4 + n) * AB_STR + l] = __builtin_bit_cast(u16, ah);
        }
    }
    __syncthreads();

    // ================= Phase 3: c_sum = ab @ c (M=64 m=(i,n), N=64 h, K=64 j) =================
    {
        const int mt3 = w & 3, nh = w >> 2;
        h8 af3[2];
        #pragma unroll
        for (int ks = 0; ks < 2; ++ks)
            af3[ks] = __builtin_bit_cast(h8,
                *(const uint4*)&s_ab[(mt3 * 16 + ml) * AB_STR + ks * 32 + q * 8]);
        #pragma unroll
        for (int nx = 0; nx < 2; ++nx) {
            const int nt = nh * 2 + nx;
            f32x4 D2 = (f32x4)0.f;
            #pragma unroll
            for (int ks = 0; ks < 2; ++ks) {
                const uint2 y0 = *(const uint2*)&s_ct[(nt * 16 + ml) * CT_STR + ks * 32 + q * 8];
                const uint2 y1 = *(const uint2*)&s_ct[(nt * 16 + ml) * CT_STR + ks * 32 + q * 8 + 4];
                const h8 bfc = frag4(y0.x, y0.y, y1.x, y1.y);
                D2 = __builtin_amdgcn_mfma_f32_16x16x32_f16(af3[ks], bfc, D2, 0, 0, 0);
            }
            // D rows: m = mt3*16 + q*4 + r -> iloc = mt3*4+q, n = r; cs[iloc][h*4+n]
            const int iloc = mt3 * 4 + q, h = nt * 16 + ml;
            *(uint2*)&s_cs[iloc * CS_STR + h * 4] =
                make_uint2(pk2(D2[0], D2[1]), pk2(D2[2], D2[3]));
        }
    }
    __syncthreads();

    // ================= Phase 4: out = cs @ Wp (M=16 i, N=64 o, K=256), waves 0-3 =================
    if (w < 4) {
        f32x4 D4 = (f32x4)0.f;
        #pragma unroll
        for (int ks = 0; ks < 8; ++ks) {
            const h8 af = __builtin_bit_cast(h8,
                *(const uint4*)&s_cs[ml * CS_STR + ks * 32 + q * 8]);
            const uint2 z0 = *(const uint2*)&s_wp[(w * 16 + ml) * WP_STR + ks * 32 + q * 8];
            const uint2 z1 = *(const uint2*)&s_wp[(w * 16 + ml) * WP_STR + ks * 32 + q * 8 + 4];
            const h8 bf4 = frag4(z0.x, z0.y, z1.x, z1.y);
            D4 = __builtin_amdgcn_mfma_f32_16x16x32_f16(af, bf4, D4, 0, 0, 0);
        }
        const int o = w * 16 + ml;
        #pragma unroll
        for (int r = 0; r < 4; ++r) {
            const int iloc = q * 4 + r;
            const int row = scope[b * 64 + i_base + iloc];
            if (row > 0) out_flat[(size_t)row * 64 + o] = D4[r];
        }
        // molecule partial: reduce over this block's 16 i, store to d_ws (agent scope)
        float s4 = D4[0] + D4[1] + D4[2] + D4[3];
        s4 += __shfl_xor(s4, 16, 64);
        s4 += __shfl_xor(s4, 32, 64);
        if (l < 16)
            __hip_atomic_store(&ws_part[(b * 4 + bx) * 64 + o], s4,
                               __ATOMIC_RELAXED, __HIP_MEMORY_SCOPE_AGENT);
    }
    // out_flat row 0 zero (single writer: block (0,0), wave 7)
    if (bx == 0 && b == 0 && w == 7) out_flat[l] = 0.f;

    __threadfence();     // release: partials visible device-wide before arrival
    __syncthreads();     // all waves' stores drained before t0's arrival bump
    if (t == 0) {
        const int old = atomicAdd(&ws_cnt[b], 1);
        s_last = (old == POISON_INT + 3 || old == 3) ? 1 : 0;  // poisoned- or zero-init ws
    }
    __syncthreads();
    if (s_last && t < 64) {   // last arriving block reduces the 4 partials
        __threadfence();      // acquire
        float v = 0.f;
        #pragma unroll
        for (int k = 0; k < 4; ++k)
            v += __hip_atomic_load(&ws_part[(b * 4 + k) * 64 + t],
                                   __ATOMIC_RELAXED, __HIP_MEMORY_SCOPE_AGENT);
        out_mol[b * 64 + t] = v;
    }
}

extern "C" void kernel_launch(void* const* d_in, const int* in_sizes, int n_in,
                              void* d_out, int out_size, void* d_ws, size_t ws_size,
                              hipStream_t stream) {
    const float* inputs   = (const float*)d_in[0];
    const int*   scope    = (const int*)d_in[1];
    // d_in[2] = scope_rev (unused: flat row index == scope value)
    const float* Wa_pair  = (const float*)d_in[3];
    const float* Wa_score = (const float*)d_in[4];
    const float* W_proj   = (const float*)d_in[5];
    float* out = (float*)d_out;

    float* ws_part = (float*)d_ws;                      // 64*4*64 floats = 65,536 B
    int*   ws_cnt  = (int*)((char*)d_ws + 65536);       // 64 ints (poison-initialized)

    // No memset dispatch: row0 + out_mol handled inside the kernel.
    dim3 grid(4, 64);   // (i-16-group, molecule): 256 blocks x 512 thr = 1 block/CU, 8 waves
    atom_attn<<<grid, 512, 0, stream>>>(inputs, scope, Wa_pair, Wa_score,
                                        W_proj, out, out + 64 * 64, ws_part, ws_cnt);
}

// Round 8
// 74.791 us; speedup vs baseline: 1.4393x; 1.4393x over previous
//
#include <hip/hip_runtime.h>
#include <stdint.h>

typedef _Float16 h2 __attribute__((ext_vector_type(2)));
typedef _Float16 h8 __attribute__((ext_vector_type(8)));
typedef float f32x4 __attribute__((ext_vector_type(4)));
typedef unsigned int u32;
typedef unsigned short u16;

// LDS strides (in elements of the buffer's type)
#define WT_STR 68    // WaT  [c'=256][h]   u16 ; 136B rows
#define PJ_STR 68    // pjT  [n*64+j][h]   u16 ; 136B rows
#define WP_STR 268   // WpT  [o=64][c2]    u16 ; 536B rows
#define PI_STR 36    // sPi  [n][i<16][h2] u32 ; 144B rows
#define CB_STR 72    // cb   [j=64][h]     u16 ; 144B rows
#define CT_STR 68    // ct   [h=64][j]     u16 ; 136B rows
#define AB_STR 72    // ab   [m=64][j]     u16 ; 144B rows
#define CS_STR 264   // cs   [i=16][c2]    u16 ; 528B rows
#define WS_STR 36    // ws   [n=4][h2]     u32 ; 144B rows

__device__ __forceinline__ u32 pk2(float a, float b) {
    return __builtin_bit_cast(u32, __builtin_amdgcn_cvt_pkrtz(a, b));
}
__device__ __forceinline__ h8 frag4(u32 a, u32 b, u32 c, u32 d) {
    return __builtin_bit_cast(h8, make_uint4(a, b, c, d));
}

__global__ __launch_bounds__(512, 1) void atom_attn(
    const float* __restrict__ inputs,
    const int*   __restrict__ scope,
    const float* __restrict__ Wa_pair,
    const float* __restrict__ Wa_score,
    const float* __restrict__ W_proj,
    float* __restrict__ out_mol,    // [64][64]
    float* __restrict__ out_flat)   // [N+1][64]
{
    // Separate buffers — no aliasing, no extra barriers. Total ~149 KB -> 1 block/CU.
    __shared__ __align__(16) u16 s_wa[256 * WT_STR];         // 34,816 B
    __shared__ __align__(16) u16 s_pj[256 * PJ_STR];         // 34,816 B
    __shared__ __align__(16) u16 s_wp[64 * WP_STR];          // 34,304 B
    __shared__ __align__(16) u32 s_pi[4 * 16 * PI_STR];      //  9,216 B
    __shared__ __align__(16) u16 s_cb[64 * CB_STR];          //  9,216 B
    __shared__ __align__(16) u16 s_ct[64 * CT_STR];          //  8,704 B
    __shared__ __align__(16) u16 s_ab[64 * AB_STR];          //  9,216 B
    __shared__ __align__(16) u16 s_cs[16 * CS_STR];          //  8,448 B
    __shared__ __align__(16) u32 s_ws[4 * WS_STR];           //    576 B

    const int t = threadIdx.x;
    const int w = t >> 6, l = t & 63;
    const int ml = l & 15, q = l >> 4;
    const int b = blockIdx.y, bx = blockIdx.x;
    const int i_base = bx * 16;

    // ================= Phase 0: stage everything (ws, c, WaT, WpT) =================
    if (t < 256) {
        if (t < 128) {  // ws transposed+packed: s_ws[n][h2] = (ws[2h2,n], ws[2h2+1,n])
            const int n = t & 3, hh = t >> 2;
            const float g0 = Wa_score[(2 * hh) * 4 + n];
            const float g1 = Wa_score[(2 * hh + 1) * 4 + n];
            s_ws[n * WS_STR + hh] = pk2(g0, g1);
        }
        {   // c rows -> cb [j][h] (h-packed) and ct [h][j] (j-pair packed)
            const int jp = (t & 31) * 2;
            const int pp = t >> 5;           // h-octant 0..7
            const int r0 = scope[b * 64 + jp];
            const int r1 = scope[b * 64 + jp + 1];
            const f32x4 a0 = *(const f32x4*)(inputs + (size_t)r0 * 64 + pp * 8);
            const f32x4 a1 = *(const f32x4*)(inputs + (size_t)r0 * 64 + pp * 8 + 4);
            const f32x4 b0 = *(const f32x4*)(inputs + (size_t)r1 * 64 + pp * 8);
            const f32x4 b1 = *(const f32x4*)(inputs + (size_t)r1 * 64 + pp * 8 + 4);
            float A[8] = {a0[0], a0[1], a0[2], a0[3], a1[0], a1[1], a1[2], a1[3]};
            float B[8] = {b0[0], b0[1], b0[2], b0[3], b1[0], b1[1], b1[2], b1[3]};
            *(uint4*)&s_cb[jp * CB_STR + pp * 8] =
                make_uint4(pk2(A[0], A[1]), pk2(A[2], A[3]), pk2(A[4], A[5]), pk2(A[6], A[7]));
            *(uint4*)&s_cb[(jp + 1) * CB_STR + pp * 8] =
                make_uint4(pk2(B[0], B[1]), pk2(B[2], B[3]), pk2(B[4], B[5]), pk2(B[6], B[7]));
            #pragma unroll
            for (int e = 0; e < 8; ++e)
                *(u32*)&s_ct[(pp * 8 + e) * CT_STR + jp] = pk2(A[e], B[e]);
        }
        {   // WpT[o][c2] f16
            const int o0 = (t & 31) * 2, seg = t >> 5;
            #pragma unroll
            for (int k2 = 0; k2 < 16; ++k2) {
                const int c0 = seg * 32 + k2 * 2;
                const float2 r0 = *(const float2*)(W_proj + c0 * 64 + o0);
                const float2 r1 = *(const float2*)(W_proj + (c0 + 1) * 64 + o0);
                *(u32*)&s_wp[o0 * WP_STR + c0]       = pk2(r0.x, r1.x);
                *(u32*)&s_wp[(o0 + 1) * WP_STR + c0] = pk2(r0.y, r1.y);
            }
        }
    } else {
        // WaT[c'][h] f16, c' = (c&3)*64 + (c>>2)  (n-major column permutation)
        const int t2 = t & 255;
        const int cg = (t2 & 127) * 2;       // even global column
        const int hh2 = t2 >> 7;             // h half
        const int cp0 = (cg & 3) * 64 + (cg >> 2);   // dest row for cg; cg+1 -> +64
        #pragma unroll
        for (int k2 = 0; k2 < 16; ++k2) {
            const int h0 = hh2 * 32 + k2 * 2;
            const float2 r0 = *(const float2*)(Wa_pair + h0 * 256 + cg);
            const float2 r1 = *(const float2*)(Wa_pair + (h0 + 1) * 256 + cg);
            *(u32*)&s_wa[cp0 * WT_STR + h0]        = pk2(r0.x, r1.x);
            *(u32*)&s_wa[(cp0 + 64) * WT_STR + h0] = pk2(r0.y, r1.y);
        }
    }
    __syncthreads();

    // ================= Phase 1: D = P^T (M=c'=256, N=j=64, K=h=64), 8 waves =================
    // wave: mq = w&3 -> mt in [mq*4, mq*4+4); jh = w>>2 -> j-tiles {2jh, 2jh+1}
    {
        const int mq = w & 3, jh = w >> 2;
        f32x4 D[4][2];
        #pragma unroll
        for (int k = 0; k < 4; ++k) { D[k][0] = (f32x4)0.f; D[k][1] = (f32x4)0.f; }
        h8 bf[2][2];
        #pragma unroll
        for (int jt = 0; jt < 2; ++jt)
            #pragma unroll
            for (int ks = 0; ks < 2; ++ks)
                bf[jt][ks] = __builtin_bit_cast(h8,
                    *(const uint4*)&s_cb[((jh * 2 + jt) * 16 + ml) * CB_STR + ks * 32 + q * 8]);
        #pragma unroll
        for (int k = 0; k < 4; ++k) {
            const int mt = mq * 4 + k;
            #pragma unroll
            for (int ks = 0; ks < 2; ++ks) {
                const uint2 x0 = *(const uint2*)&s_wa[(mt * 16 + ml) * WT_STR + ks * 32 + q * 8];
                const uint2 x1 = *(const uint2*)&s_wa[(mt * 16 + ml) * WT_STR + ks * 32 + q * 8 + 4];
                const h8 af = frag4(x0.x, x0.y, x1.x, x1.y);
                D[k][0] = __builtin_amdgcn_mfma_f32_16x16x32_f16(af, bf[0][ks], D[k][0], 0, 0, 0);
                D[k][1] = __builtin_amdgcn_mfma_f32_16x16x32_f16(af, bf[1][ks], D[k][1], 0, 0, 0);
            }
        }
        // store P^T (separate buffers -> no barrier needed before stores)
        #pragma unroll
        for (int k = 0; k < 4; ++k) {
            const int mt = mq * 4 + k;
            const int nb = mt >> 2, h0 = (mt & 3) * 16 + q * 4;
            #pragma unroll
            for (int jt = 0; jt < 2; ++jt) {
                const int jtile = jh * 2 + jt;
                const int j = jtile * 16 + ml;
                const u32 p0 = pk2(D[k][jt][0], D[k][jt][1]);
                const u32 p1 = pk2(D[k][jt][2], D[k][jt][3]);
                *(uint2*)&s_pj[(nb * 64 + j) * PJ_STR + h0] = make_uint2(p0, p1);
                if (jtile == bx)   // j == i_base + ml -> this block's P_i rows
                    *(uint2*)&s_pi[(nb * 16 + ml) * PI_STR + (h0 >> 1)] = make_uint2(p0, p1);
            }
        }
    }
    __syncthreads();

    // ================= Phase 2: scores (wave = (n, i-half), lane = j) =================
    {
        const int n = w & 3, ih = w >> 2;
        u32 pj_u[32];
        #pragma unroll
        for (int k = 0; k < 16; ++k) {
            const uint2 v = *(const uint2*)&s_pj[(n * 64 + l) * PJ_STR + k * 4];
            pj_u[2 * k] = v.x; pj_u[2 * k + 1] = v.y;
        }
        u32 ws_u[32];
        #pragma unroll
        for (int k = 0; k < 8; ++k) {
            const uint4 v = *(const uint4*)&s_ws[n * WS_STR + k * 4];
            ws_u[4 * k] = v.x; ws_u[4 * k + 1] = v.y; ws_u[4 * k + 2] = v.z; ws_u[4 * k + 3] = v.w;
        }
        const h2 zero2 = {(_Float16)0.f, (_Float16)0.f};
        #pragma unroll
        for (int ii = 0; ii < 8; ++ii) {
            const int iloc = ih * 8 + ii;
            const u32* pir = &s_pi[(n * 16 + iloc) * PI_STR];
            float s0 = 0.f, s1 = 0.f;
            #pragma unroll
            for (int c8 = 0; c8 < 8; ++c8) {
                const uint4 pv = *(const uint4*)&pir[c8 * 4];
                const u32 pe[4] = {pv.x, pv.y, pv.z, pv.w};
                #pragma unroll
                for (int e = 0; e < 4; ++e) {
                    const h2 pi2 = __builtin_bit_cast(h2, pe[e]);
                    const h2 pj2 = __builtin_bit_cast(h2, pj_u[c8 * 4 + e]);
                    h2 tv = pi2 + pj2;                         // v_pk_add_f16
                    tv = __builtin_elementwise_max(tv, zero2); // v_pk_max_f16
                    if (e & 1)
                        s1 = __builtin_amdgcn_fdot2(tv,
                                __builtin_bit_cast(h2, ws_u[c8 * 4 + e]), s1, false);
                    else
                        s0 = __builtin_amdgcn_fdot2(tv,
                                __builtin_bit_cast(h2, ws_u[c8 * 4 + e]), s0, false);
                }
            }
            const float s = s0 + s1;
            const float a = 1.f / (1.f + __expf(-s));
            const _Float16 ah = (_Float16)a;
            s_ab[(iloc * 4 + n) * AB_STR + l] = __builtin_bit_cast(u16, ah);
        }
    }
    __syncthreads();

    // ================= Phase 3: c_sum = ab @ c (M=64 m=(i,n), N=64 h, K=64 j) =================
    {
        const int mt3 = w & 3, nh = w >> 2;
        h8 af3[2];
        #pragma unroll
        for (int ks = 0; ks < 2; ++ks)
            af3[ks] = __builtin_bit_cast(h8,
                *(const uint4*)&s_ab[(mt3 * 16 + ml) * AB_STR + ks * 32 + q * 8]);
        #pragma unroll
        for (int nx = 0; nx < 2; ++nx) {
            const int nt = nh * 2 + nx;
            f32x4 D2 = (f32x4)0.f;
            #pragma unroll
            for (int ks = 0; ks < 2; ++ks) {
                const uint2 y0 = *(const uint2*)&s_ct[(nt * 16 + ml) * CT_STR + ks * 32 + q * 8];
                const uint2 y1 = *(const uint2*)&s_ct[(nt * 16 + ml) * CT_STR + ks * 32 + q * 8 + 4];
                const h8 bfc = frag4(y0.x, y0.y, y1.x, y1.y);
                D2 = __builtin_amdgcn_mfma_f32_16x16x32_f16(af3[ks], bfc, D2, 0, 0, 0);
            }
            // D rows: m = mt3*16 + q*4 + r -> iloc = mt3*4+q, n = r; cs[iloc][h*4+n]
            const int iloc = mt3 * 4 + q, h = nt * 16 + ml;
            *(uint2*)&s_cs[iloc * CS_STR + h * 4] =
                make_uint2(pk2(D2[0], D2[1]), pk2(D2[2], D2[3]));
        }
    }
    __syncthreads();

    // ================= Phase 4: out = cs @ Wp (M=16 i, N=64 o, K=256), waves 0-3 =================
    if (w < 4) {
        f32x4 D4 = (f32x4)0.f;
        #pragma unroll
        for (int ks = 0; ks < 8; ++ks) {
            const h8 af = __builtin_bit_cast(h8,
                *(const uint4*)&s_cs[ml * CS_STR + ks * 32 + q * 8]);
            const uint2 z0 = *(const uint2*)&s_wp[(w * 16 + ml) * WP_STR + ks * 32 + q * 8];
            const uint2 z1 = *(const uint2*)&s_wp[(w * 16 + ml) * WP_STR + ks * 32 + q * 8 + 4];
            const h8 bf4 = frag4(z0.x, z0.y, z1.x, z1.y);
            D4 = __builtin_amdgcn_mfma_f32_16x16x32_f16(af, bf4, D4, 0, 0, 0);
        }
        const int o = w * 16 + ml;
        #pragma unroll
        for (int r = 0; r < 4; ++r) {
            const int iloc = q * 4 + r;
            const int row = scope[b * 64 + i_base + iloc];
            if (row > 0) out_flat[(size_t)row * 64 + o] = D4[r];
        }
        float s4 = D4[0] + D4[1] + D4[2] + D4[3];
        s4 += __shfl_xor(s4, 16, 64);
        s4 += __shfl_xor(s4, 32, 64);
        if (l < 16) atomicAdd(out_mol + b * 64 + o, s4);
    }
}

extern "C" void kernel_launch(void* const* d_in, const int* in_sizes, int n_in,
                              void* d_out, int out_size, void* d_ws, size_t ws_size,
                              hipStream_t stream) {
    const float* inputs   = (const float*)d_in[0];
    const int*   scope    = (const int*)d_in[1];
    // d_in[2] = scope_rev (unused: flat row index == scope value)
    const float* Wa_pair  = (const float*)d_in[3];
    const float* Wa_score = (const float*)d_in[4];
    const float* W_proj   = (const float*)d_in[5];
    float* out = (float*)d_out;

    // zero only what isn't fully overwritten: out_mol [64*64] + flat row 0 [64]
    (void)hipMemsetAsync(d_out, 0, (64 * 64 + 64) * sizeof(float), stream);

    dim3 grid(4, 64);   // (i-16-group, molecule): 256 blocks x 512 thr = 1 block/CU, 8 waves
    atom_attn<<<grid, 512, 0, stream>>>(inputs, scope, Wa_pair, Wa_score,
                                        W_proj, out, out + 64 * 64);
}